// Round 3
// baseline (1584.034 us; speedup 1.0000x reference)
//
#include <hip/hip_runtime.h>
#include <hip/hip_bf16.h>
#include <math.h>

#define B 64
#define L 2048
#define C 1024          // D_K = D_Q
#define NH 8
#define DK 128
#define SCALE 0.08838834764831845f   // 1/sqrt(128)

// ---------------------------------------------------------------------------
// k_qs: qs[b, j] = bias[j] + sum_c q[b,c] * wq[j,c]   (64 x 1024)
// 256 blocks x 256 thr; wave owns one j-row, W in regs, loop b.
__global__ void k_qs(const float* __restrict__ q, const float* __restrict__ wq,
                     const float* __restrict__ bq, float* __restrict__ qs) {
    int t = threadIdx.x, w = t >> 6, lane = t & 63;
    int j = blockIdx.x * 4 + w;
    float4 W[4];
#pragma unroll
    for (int kk = 0; kk < 4; kk++)
        W[kk] = *(const float4*)&wq[(size_t)j * C + kk * 256 + lane * 4];
    float bj = bq[j];
    for (int b = 0; b < B; b++) {
        float s = 0.f;
#pragma unroll
        for (int kk = 0; kk < 4; kk++) {
            float4 qv = *(const float4*)&q[(size_t)b * C + kk * 256 + lane * 4];
            s += W[kk].x * qv.x + W[kk].y * qv.y + W[kk].z * qv.z + W[kk].w * qv.w;
        }
#pragma unroll
        for (int off = 32; off; off >>= 1) s += __shfl_xor(s, off, 64);
        if (lane == 0) qs[(size_t)b * C + j] = s + bj;
    }
}

// ---------------------------------------------------------------------------
// k_qtilde: qtilde[b,n,c] = SCALE * sum_d qs[b, n*128+d] * wk[n*128+d, c]
// grid (n*cc = 32, bg = 8) = 256 blocks; block: head n, c-chunk of 256, 8 b's.
__global__ void k_qtilde(const float* __restrict__ qs, const float* __restrict__ wk,
                         float* __restrict__ qtilde) {
    int n = blockIdx.x >> 2, cc = blockIdx.x & 3, bg = blockIdx.y;
    int t = threadIdx.x;
    int c = cc * 256 + t;
    __shared__ float qss[8][128];
    for (int p = 0; p < 4; p++) {
        int e = p * 256 + t;
        int i = e >> 7, d = e & 127;
        qss[i][d] = qs[(size_t)(bg * 8 + i) * C + n * DK + d];
    }
    __syncthreads();
    float acc[8];
#pragma unroll
    for (int i = 0; i < 8; i++) acc[i] = 0.f;
    for (int d = 0; d < DK; d++) {
        float wv = wk[(size_t)(n * DK + d) * C + c];
#pragma unroll
        for (int i = 0; i < 8; i++) acc[i] += qss[i][d] * wv;
    }
#pragma unroll
    for (int i = 0; i < 8; i++)
        qtilde[((size_t)(bg * 8 + i) * NH + n) * C + c] = acc[i] * SCALE;
}

// ---------------------------------------------------------------------------
// k_fused2: one streaming pass over k. Direct exp (no max: |s| bounded, softmax
// shift-invariant, f32 safe) -> partials combine by plain addition.
// 1024 thr = 16 waves: chunk = w>>2 (128 rows each), hp = w&3 (heads 2hp,2hp+1).
// Lane owns 16 contiguous c. No barriers in main loop; LDS phased merge at end.
__global__ __launch_bounds__(1024, 1) void k_fused2(
    const float* __restrict__ kmat, const float* __restrict__ qtilde,
    const unsigned char* __restrict__ mask,
    float* __restrict__ rawsc,            // (n*B + b)*L + l  (raw scores)
    float* __restrict__ accpart,          // [b][lp][n][C] f32
    float* __restrict__ zpart) {          // [b][lp][n]
    const int b = blockIdx.x, lp = blockIdx.y;
    const int t = threadIdx.x, w = t >> 6, lane = t & 63;
    const int chunk = w >> 2, hp = w & 3;
    const int l0 = lp * 512 + chunk * 128;
    const int c0 = lane * 16;

    __shared__ float ctxl[NH * C];        // 32 KB
    __shared__ float zl[NH];

    float4 qt[2][4];
#pragma unroll
    for (int j = 0; j < 2; j++)
#pragma unroll
        for (int kk = 0; kk < 4; kk++)
            qt[j][kk] = *(const float4*)&qtilde[((size_t)b * NH + 2 * hp + j) * C + c0 + kk * 4];

    float4 acc[2][4];
#pragma unroll
    for (int j = 0; j < 2; j++)
#pragma unroll
        for (int kk = 0; kk < 4; kk++) acc[j][kk] = make_float4(0.f, 0.f, 0.f, 0.f);
    float zacc = 0.f;

    const float* kp = kmat + ((size_t)b * L + l0) * C + c0;
    float4 kv[2][4];
#pragma unroll
    for (int kk = 0; kk < 4; kk++) kv[0][kk] = *(const float4*)(kp + kk * 4);

    for (int rb = 0; rb < 16; rb++) {
        unsigned long long mw =
            *(const unsigned long long*)&mask[(size_t)b * L + l0 + rb * 8];
        float ss[8];
#pragma unroll
        for (int rr = 0; rr < 8; rr++) {
            const int r = rb * 8 + rr;
            const int cur = r & 1;
            if (r < 127) {
                const float* np = kp + (size_t)(r + 1) * C;
#pragma unroll
                for (int kk = 0; kk < 4; kk++)
                    kv[cur ^ 1][kk] = *(const float4*)(np + kk * 4);
            }
            // per-lane partial dots for the 2 heads
            float s0 = 0.f, s1 = 0.f;
#pragma unroll
            for (int kk = 0; kk < 4; kk++) {
                float4 kq = kv[cur][kk];
                s0 += qt[0][kk].x * kq.x + qt[0][kk].y * kq.y + qt[0][kk].z * kq.z + qt[0][kk].w * kq.w;
                s1 += qt[1][kk].x * kq.x + qt[1][kk].y * kq.y + qt[1][kk].z * kq.z + qt[1][kk].w * kq.w;
            }
            // split-butterfly: lane ends with full sum of head 2hp + (lane&1)
            float keep = (lane & 1) ? s1 : s0;
            float give = (lane & 1) ? s0 : s1;
            float v = keep + __shfl_xor(give, 1, 64);
            v += __shfl_xor(v, 2, 64);
            v += __shfl_xor(v, 4, 64);
            v += __shfl_xor(v, 8, 64);
            v += __shfl_xor(v, 16, 64);
            v += __shfl_xor(v, 32, 64);
            ss[rr] = v;
            float madd = ((mw >> (8 * rr)) & 0xffULL) ? -INFINITY : 0.0f;
            float p = __expf(v + madd);
            zacc += p;
            float po = __shfl_xor(p, 1, 64);
            float pa = (lane & 1) ? po : p;   // weight of head 2hp
            float pb = (lane & 1) ? p : po;   // weight of head 2hp+1
#pragma unroll
            for (int kk = 0; kk < 4; kk++) {
                float4 kq = kv[cur][kk];
                acc[0][kk].x += pa * kq.x; acc[0][kk].y += pa * kq.y;
                acc[0][kk].z += pa * kq.z; acc[0][kk].w += pa * kq.w;
                acc[1][kk].x += pb * kq.x; acc[1][kk].y += pb * kq.y;
                acc[1][kk].z += pb * kq.z; acc[1][kk].w += pb * kq.w;
            }
        }
        // raw-score store: lanes 0..3 hold everything needed (static reg indices)
        if (lane < 4) {
            int head = 2 * hp + (lane & 1);
            float4 olo = make_float4(ss[0], ss[1], ss[2], ss[3]);
            float4 ohi = make_float4(ss[4], ss[5], ss[6], ss[7]);
            float4 o = (lane >> 1) ? ohi : olo;
            *(float4*)&rawsc[((size_t)head * B + b) * L + l0 + rb * 8 + ((lane >> 1) << 2)] = o;
        }
    }

    // epilogue: phased LDS merge across the 4 row-chunks (plain adds; no max)
    __syncthreads();
    for (int ph = 0; ph < 4; ph++) {
        if (chunk == ph) {
            if (ph == 0) {
#pragma unroll
                for (int j = 0; j < 2; j++)
#pragma unroll
                    for (int kk = 0; kk < 4; kk++)
                        *(float4*)&ctxl[(2 * hp + j) * C + c0 + kk * 4] = acc[j][kk];
                if (lane < 2) zl[2 * hp + lane] = zacc;
            } else {
#pragma unroll
                for (int j = 0; j < 2; j++)
#pragma unroll
                    for (int kk = 0; kk < 4; kk++) {
                        float4 o = *(const float4*)&ctxl[(2 * hp + j) * C + c0 + kk * 4];
                        float4 a = acc[j][kk];
                        o.x += a.x; o.y += a.y; o.z += a.z; o.w += a.w;
                        *(float4*)&ctxl[(2 * hp + j) * C + c0 + kk * 4] = o;
                    }
                if (lane < 2) zl[2 * hp + lane] += zacc;
            }
        }
        __syncthreads();
    }
    float* ap = accpart + ((size_t)b * 4 + lp) * (NH * C);
#pragma unroll
    for (int i = 0; i < 2; i++) {
        int idx = (t * 2 + i) * 4;
        *(float4*)&ap[idx] = *(const float4*)&ctxl[idx];
    }
    if (t < NH) zpart[((size_t)b * 4 + lp) * NH + t] = zl[t];
}

// ---------------------------------------------------------------------------
// k_combine: ctx[b,n,c] = (sum_lp accpart) / Z;  Zinv[n*B+b] stored for attnnorm.
__global__ void k_combine(const float* __restrict__ accpart, const float* __restrict__ zpart,
                          float* __restrict__ ctx, float* __restrict__ Zinv) {
    int b = blockIdx.x, cq = blockIdx.y;
    int t = threadIdx.x;
    int c = cq * 256 + t;
    __shared__ float zi[NH];
    if (t < NH) {
        float z = 0.f;
#pragma unroll
        for (int lpp = 0; lpp < 4; lpp++) z += zpart[((size_t)b * 4 + lpp) * NH + t];
        float inv = 1.0f / z;
        zi[t] = inv;
        if (cq == 0) Zinv[t * B + b] = inv;
    }
    __syncthreads();
#pragma unroll
    for (int n = 0; n < NH; n++) {
        float s = 0.f;
#pragma unroll
        for (int lpp = 0; lpp < 4; lpp++)
            s += accpart[(((size_t)b * 4 + lpp) * NH + n) * C + c];
        ctx[((size_t)b * NH + n) * C + c] = s * zi[n];
    }
}

// ---------------------------------------------------------------------------
// k_attnnorm: attn[row, l] = mask ? 0 : exp(raw) * Zinv   (in place, M = 0)
__global__ void k_attnnorm(float* __restrict__ attn, const unsigned char* __restrict__ mask,
                           const float* __restrict__ Zinv) {
    int row = blockIdx.x;            // n*64 + b
    int b = row & 63;
    int t = threadIdx.x;
    float Zi = Zinv[row];
    float* p = attn + (size_t)row * L;
    const unsigned char* mr = mask + (size_t)b * L;
#pragma unroll
    for (int j = 0; j < 2; j++) {
        int pos = j * 1024 + t * 4;
        float4 s = *(const float4*)&p[pos];
        uchar4 mv = *(const uchar4*)&mr[pos];
        float4 o;
        o.x = mv.x ? 0.f : __expf(s.x) * Zi;
        o.y = mv.y ? 0.f : __expf(s.y) * Zi;
        o.z = mv.z ? 0.f : __expf(s.z) * Zi;
        o.w = mv.w ? 0.f : __expf(s.w) * Zi;
        *(float4*)&p[pos] = o;
    }
}

// ---------------------------------------------------------------------------
// k_out: output[b, j] = bv[j] + sum_c wv[j,c] * ctx[b, n(j), c]
// 256 blocks x 256 thr; wave owns one j-row.
__global__ void k_out(const float* __restrict__ ctx, const float* __restrict__ wv,
                      const float* __restrict__ bv, float* __restrict__ out) {
    int t = threadIdx.x, w = t >> 6, lane = t & 63;
    int j = blockIdx.x * 4 + w;
    int n = j >> 7;
    float4 W[4];
#pragma unroll
    for (int kk = 0; kk < 4; kk++)
        W[kk] = *(const float4*)&wv[(size_t)j * C + kk * 256 + lane * 4];
    float bj = bv[j];
    for (int b = 0; b < B; b++) {
        float s = 0.f;
#pragma unroll
        for (int kk = 0; kk < 4; kk++) {
            float4 cv = *(const float4*)&ctx[((size_t)b * NH + n) * C + kk * 256 + lane * 4];
            s += W[kk].x * cv.x + W[kk].y * cv.y + W[kk].z * cv.z + W[kk].w * cv.w;
        }
#pragma unroll
        for (int off = 32; off; off >>= 1) s += __shfl_xor(s, off, 64);
        if (lane == 0) out[(size_t)b * (NH * DK) + j] = s + bj;
    }
}

// ---------------------------------------------------------------------------
extern "C" void kernel_launch(void* const* d_in, const int* in_sizes, int n_in,
                              void* d_out, int out_size, void* d_ws, size_t ws_size,
                              hipStream_t stream) {
    const float* q    = (const float*)d_in[0];
    const float* kmat = (const float*)d_in[1];
    const unsigned char* mask = (const unsigned char*)d_in[2];
    const float* wq = (const float*)d_in[3];
    const float* bq = (const float*)d_in[4];
    const float* wk = (const float*)d_in[5];
    // d_in[6] = w_ks_b: softmax-invariant -> unused.
    const float* wv = (const float*)d_in[7];
    const float* bv = (const float*)d_in[8];

    float* out  = (float*)d_out;            // (64, 1024)
    float* attn = out + B * NH * DK;        // (8*64, 2048) raw scores -> softmax

    float* ws      = (float*)d_ws;
    // region 0 (65536 floats): qs (dead after k_qtilde), then overlaid zpart/Zinv.
    float* qs      = ws;
    float* zpart   = ws;                     // 2048 floats (64*4*8)
    float* Zinv    = ws + 2048;              // 512 floats
    // region 1: qtilde (524288 floats), reused as ctx after k_fused2.
    float* qtilde  = ws + 65536;
    float* ctx     = qtilde;
    // region 2: accpart (64*4*8*1024 = 2097152 floats)
    float* accpart = ws + 65536 + 524288;

    hipLaunchKernelGGL(k_qs, dim3(256), dim3(256), 0, stream, q, wq, bq, qs);
    hipLaunchKernelGGL(k_qtilde, dim3(32, 8), dim3(256), 0, stream, qs, wk, qtilde);
    hipLaunchKernelGGL(k_fused2, dim3(64, 4), dim3(1024), 0, stream,
                       kmat, qtilde, mask, attn, accpart, zpart);
    hipLaunchKernelGGL(k_combine, dim3(64, 4), dim3(256), 0, stream,
                       accpart, zpart, ctx, Zinv);
    hipLaunchKernelGGL(k_attnnorm, dim3(512), dim3(256), 0, stream, attn, mask, Zinv);
    hipLaunchKernelGGL(k_out, dim3(256), dim3(256), 0, stream, ctx, wv, bv, out);
}

// Round 5
// 243.604 us; speedup vs baseline: 6.5025x; 6.5025x over previous
//
#include <hip/hip_runtime.h>
#include <hip/hip_bf16.h>
#include <math.h>

#define B 64
#define L 2048
#define C 1024          // D_K = D_Q
#define NH 8
#define DK 128
#define SCALE 0.08838834764831845f   // 1/sqrt(128)

// ---------------------------------------------------------------------------
// k_qs: qs[b, j] = bias[j] + sum_c q[b,c] * wq[j,c]   (64 x 1024)
__global__ void k_qs(const float* __restrict__ q, const float* __restrict__ wq,
                     const float* __restrict__ bq, float* __restrict__ qs) {
    int t = threadIdx.x, w = t >> 6, lane = t & 63;
    int j = blockIdx.x * 4 + w;
    float4 W[4];
#pragma unroll
    for (int kk = 0; kk < 4; kk++)
        W[kk] = *(const float4*)&wq[(size_t)j * C + kk * 256 + lane * 4];
    float bj = bq[j];
    for (int b = 0; b < B; b++) {
        float s = 0.f;
#pragma unroll
        for (int kk = 0; kk < 4; kk++) {
            float4 qv = *(const float4*)&q[(size_t)b * C + kk * 256 + lane * 4];
            s += W[kk].x * qv.x + W[kk].y * qv.y + W[kk].z * qv.z + W[kk].w * qv.w;
        }
#pragma unroll
        for (int off = 32; off; off >>= 1) s += __shfl_xor(s, off, 64);
        if (lane == 0) qs[(size_t)b * C + j] = s + bj;
    }
}

// ---------------------------------------------------------------------------
// k_qtilde: qtilde[b,n,c] = SCALE * sum_d qs[b, n*128+d] * wk[n*128+d, c]
__global__ void k_qtilde(const float* __restrict__ qs, const float* __restrict__ wk,
                         float* __restrict__ qtilde) {
    int n = blockIdx.x >> 2, cc = blockIdx.x & 3, bg = blockIdx.y;
    int t = threadIdx.x;
    int c = cc * 256 + t;
    __shared__ float qss[8][128];
    for (int p = 0; p < 4; p++) {
        int e = p * 256 + t;
        int i = e >> 7, d = e & 127;
        qss[i][d] = qs[(size_t)(bg * 8 + i) * C + n * DK + d];
    }
    __syncthreads();
    float acc[8];
#pragma unroll
    for (int i = 0; i < 8; i++) acc[i] = 0.f;
    for (int d = 0; d < DK; d++) {
        float wv = wk[(size_t)(n * DK + d) * C + c];
#pragma unroll
        for (int i = 0; i < 8; i++) acc[i] += qss[i][d] * wv;
    }
#pragma unroll
    for (int i = 0; i < 8; i++)
        qtilde[((size_t)(bg * 8 + i) * NH + n) * C + c] = acc[i] * SCALE;
}

// ---------------------------------------------------------------------------
// k_fused3: one streaming pass over k. 512 thr = 8 waves = 4 chunks x 2 hg.
// Wave: 4 heads (hg*4..+3) x 128 rows. Lane owns c-slots {kk*256+lane*4 .. +3}.
// Direct exp (softmax shift-invariance; f32 safe) -> partials add plainly.
// Stores p = exp(s) (masked -> 0) to pout; attnnorm is then a pure scale.
__global__ __launch_bounds__(512, 2) void k_fused3(
    const float* __restrict__ kmat, const float* __restrict__ qtilde,
    const unsigned char* __restrict__ mask,
    float* __restrict__ pout,             // (n*B + b)*L + l : exp(score)
    float* __restrict__ accpart,          // [b][lp][n][C]
    float* __restrict__ zpart) {          // [b][lp][n]
    const int b = blockIdx.x, lp = blockIdx.y;
    const int t = threadIdx.x, w = t >> 6, lane = t & 63;
    const int chunk = w >> 1;            // 0..3 (128 rows each)
    const int hg = w & 1;                // 0..1 (heads hg*4..hg*4+3)
    const int l0 = lp * 512 + chunk * 128;
    const int hl = lane & 3;

    __shared__ float ctxl[NH * C];       // 32 KB
    __shared__ float zl[NH];

    float4 qt[4][4];
#pragma unroll
    for (int j = 0; j < 4; j++)
#pragma unroll
        for (int kk = 0; kk < 4; kk++)
            qt[j][kk] = *(const float4*)&qtilde[((size_t)b * NH + hg * 4 + j) * C + kk * 256 + lane * 4];

    float4 acc[4][4];
#pragma unroll
    for (int j = 0; j < 4; j++)
#pragma unroll
        for (int kk = 0; kk < 4; kk++) acc[j][kk] = make_float4(0.f, 0.f, 0.f, 0.f);
    float zacc = 0.f;

    const float* kp = kmat + ((size_t)b * L + l0) * C + lane * 4;
    const unsigned char* mp = mask + (size_t)b * L + l0;

    float4 kv[2][4];
#pragma unroll
    for (int kk = 0; kk < 4; kk++) kv[0][kk] = *(const float4*)(kp + kk * 256);

    for (int rb = 0; rb < 32; rb++) {
        uchar4 mb = *(const uchar4*)&mp[rb * 4];
        float ss[4];
#pragma unroll
        for (int rr = 0; rr < 4; rr++) {
            const int r = rb * 4 + rr;
            const int cur = r & 1;
            if (r < 127) {
                const float* np = kp + (size_t)(r + 1) * C;
#pragma unroll
                for (int kk = 0; kk < 4; kk++)
                    kv[cur ^ 1][kk] = *(const float4*)(np + kk * 256);
            }
            float s0 = 0.f, s1 = 0.f, s2 = 0.f, s3 = 0.f;
#pragma unroll
            for (int kk = 0; kk < 4; kk++) {
                float4 kq = kv[cur][kk];
                s0 += qt[0][kk].x * kq.x + qt[0][kk].y * kq.y + qt[0][kk].z * kq.z + qt[0][kk].w * kq.w;
                s1 += qt[1][kk].x * kq.x + qt[1][kk].y * kq.y + qt[1][kk].z * kq.z + qt[1][kk].w * kq.w;
                s2 += qt[2][kk].x * kq.x + qt[2][kk].y * kq.y + qt[2][kk].z * kq.z + qt[2][kk].w * kq.w;
                s3 += qt[3][kk].x * kq.x + qt[3][kk].y * kq.y + qt[3][kk].z * kq.z + qt[3][kk].w * kq.w;
            }
            // butterfly: lane ends with full score of head (lane&3)
            float a01 = (lane & 1) ? s1 : s0;
            float g01 = (lane & 1) ? s0 : s1;
            float a23 = (lane & 1) ? s3 : s2;
            float g23 = (lane & 1) ? s2 : s3;
            float u  = a01 + __shfl_xor(g01, 1, 64);   // head (lane&1)
            float v2 = a23 + __shfl_xor(g23, 1, 64);   // head 2+(lane&1)
            float keep = (lane & 2) ? v2 : u;
            float give = (lane & 2) ? u : v2;
            float v = keep + __shfl_xor(give, 2, 64);  // head (lane&3)
            v += __shfl_xor(v, 4, 64);
            v += __shfl_xor(v, 8, 64);
            v += __shfl_xor(v, 16, 64);
            v += __shfl_xor(v, 32, 64);
            unsigned char mk = (rr == 0) ? mb.x : (rr == 1) ? mb.y : (rr == 2) ? mb.z : mb.w;
            float p = __expf(mk ? -INFINITY : v);
            zacc += p;      // NOTE: p is already the FULL row sum -> zacc is full
            ss[rr] = p;     //       chunk-partial Z for head (lane&3). No further
                            //       cross-lane reduction needed (round-4 bug: x16).
            // broadcast (permuted): pj = p of head (lane&3)^j
            float p1 = __shfl_xor(p, 1, 64);
            float p2 = __shfl_xor(p, 2, 64);
            float p3 = __shfl_xor(p1, 2, 64);
#pragma unroll
            for (int kk = 0; kk < 4; kk++) {
                float4 kq = kv[cur][kk];
                acc[0][kk].x += p  * kq.x; acc[0][kk].y += p  * kq.y; acc[0][kk].z += p  * kq.z; acc[0][kk].w += p  * kq.w;
                acc[1][kk].x += p1 * kq.x; acc[1][kk].y += p1 * kq.y; acc[1][kk].z += p1 * kq.z; acc[1][kk].w += p1 * kq.w;
                acc[2][kk].x += p2 * kq.x; acc[2][kk].y += p2 * kq.y; acc[2][kk].z += p2 * kq.z; acc[2][kk].w += p2 * kq.w;
                acc[3][kk].x += p3 * kq.x; acc[3][kk].y += p3 * kq.y; acc[3][kk].z += p3 * kq.z; acc[3][kk].w += p3 * kq.w;
            }
        }
        if (lane < 4) {
            float4 o = make_float4(ss[0], ss[1], ss[2], ss[3]);
            *(float4*)&pout[((size_t)(hg * 4 + lane) * B + b) * L + l0 + rb * 4] = o;
        }
    }

    // phased LDS merge across chunks; un-permute head mapping h = hg*4+(hl^j)
    __syncthreads();
    for (int ph = 0; ph < 4; ph++) {
        if (chunk == ph) {
#pragma unroll
            for (int j = 0; j < 4; j++) {
                int h = hg * 4 + (hl ^ j);
                float* dst = &ctxl[(size_t)h * C + lane * 4];
                if (ph == 0) {
#pragma unroll
                    for (int kk = 0; kk < 4; kk++)
                        *(float4*)&dst[kk * 256] = acc[j][kk];
                } else {
#pragma unroll
                    for (int kk = 0; kk < 4; kk++) {
                        float4 o = *(const float4*)&dst[kk * 256];
                        float4 a = acc[j][kk];
                        o.x += a.x; o.y += a.y; o.z += a.z; o.w += a.w;
                        *(float4*)&dst[kk * 256] = o;
                    }
                }
            }
            if (lane < 4) {
                if (ph == 0) zl[hg * 4 + lane] = zacc;
                else         zl[hg * 4 + lane] += zacc;
            }
        }
        __syncthreads();
    }
    float* ap = accpart + ((size_t)b * 4 + lp) * (NH * C);
#pragma unroll
    for (int i = 0; i < 4; i++) {
        int idx = t * 16 + i * 4;
        *(float4*)&ap[idx] = *(const float4*)&ctxl[idx];
    }
    if (t < NH) zpart[((size_t)b * 4 + lp) * NH + t] = zl[t];
}

// ---------------------------------------------------------------------------
// k_combine: ctx[b,n,c] = (sum_lp accpart) / Z;  Zinv[n*B+b] stored for attnnorm.
__global__ void k_combine(const float* __restrict__ accpart, const float* __restrict__ zpart,
                          float* __restrict__ ctx, float* __restrict__ Zinv) {
    int b = blockIdx.x, cq = blockIdx.y;
    int t = threadIdx.x;
    int c = cq * 256 + t;
    __shared__ float zi[NH];
    if (t < NH) {
        float z = 0.f;
#pragma unroll
        for (int lpp = 0; lpp < 4; lpp++) z += zpart[((size_t)b * 4 + lpp) * NH + t];
        float inv = 1.0f / z;
        zi[t] = inv;
        if (cq == 0) Zinv[t * B + b] = inv;
    }
    __syncthreads();
#pragma unroll
    for (int n = 0; n < NH; n++) {
        float s = 0.f;
#pragma unroll
        for (int lpp = 0; lpp < 4; lpp++)
            s += accpart[(((size_t)b * 4 + lpp) * NH + n) * C + c];
        ctx[((size_t)b * NH + n) * C + c] = s * zi[n];
    }
}

// ---------------------------------------------------------------------------
// k_attnnorm: attn[row, l] = p * Zinv   (pure scale; p already exp'd + masked)
__global__ void k_attnnorm(float* __restrict__ attn, const float* __restrict__ Zinv) {
    int row = blockIdx.x;            // n*64 + b
    int t = threadIdx.x;
    float Zi = Zinv[row];
    float* p = attn + (size_t)row * L;
#pragma unroll
    for (int j = 0; j < 2; j++) {
        int pos = j * 1024 + t * 4;
        float4 s = *(const float4*)&p[pos];
        s.x *= Zi; s.y *= Zi; s.z *= Zi; s.w *= Zi;
        *(float4*)&p[pos] = s;
    }
}

// ---------------------------------------------------------------------------
// k_out: output[b, j] = bv[j] + sum_c wv[j,c] * ctx[b, n(j), c]
__global__ void k_out(const float* __restrict__ ctx, const float* __restrict__ wv,
                      const float* __restrict__ bv, float* __restrict__ out) {
    int t = threadIdx.x, w = t >> 6, lane = t & 63;
    int j = blockIdx.x * 4 + w;
    int n = j >> 7;
    float4 W[4];
#pragma unroll
    for (int kk = 0; kk < 4; kk++)
        W[kk] = *(const float4*)&wv[(size_t)j * C + kk * 256 + lane * 4];
    float bj = bv[j];
    for (int b = 0; b < B; b++) {
        float s = 0.f;
#pragma unroll
        for (int kk = 0; kk < 4; kk++) {
            float4 cv = *(const float4*)&ctx[((size_t)b * NH + n) * C + kk * 256 + lane * 4];
            s += W[kk].x * cv.x + W[kk].y * cv.y + W[kk].z * cv.z + W[kk].w * cv.w;
        }
#pragma unroll
        for (int off = 32; off; off >>= 1) s += __shfl_xor(s, off, 64);
        if (lane == 0) out[(size_t)b * (NH * DK) + j] = s + bj;
    }
}

// ---------------------------------------------------------------------------
extern "C" void kernel_launch(void* const* d_in, const int* in_sizes, int n_in,
                              void* d_out, int out_size, void* d_ws, size_t ws_size,
                              hipStream_t stream) {
    const float* q    = (const float*)d_in[0];
    const float* kmat = (const float*)d_in[1];
    const unsigned char* mask = (const unsigned char*)d_in[2];
    const float* wq = (const float*)d_in[3];
    const float* bq = (const float*)d_in[4];
    const float* wk = (const float*)d_in[5];
    // d_in[6] = w_ks_b: softmax-invariant -> unused.
    const float* wv = (const float*)d_in[7];
    const float* bv = (const float*)d_in[8];

    float* out  = (float*)d_out;            // (64, 1024)
    float* attn = out + B * NH * DK;        // (8*64, 2048): exp(s) -> scaled

    float* ws      = (float*)d_ws;
    float* qs      = ws;                     // 65536 floats (dead after k_qtilde)
    float* zpart   = ws;                     // 2048 floats overlay
    float* Zinv    = ws + 2048;              // 512 floats
    float* qtilde  = ws + 65536;             // 524288 floats, reused as ctx
    float* ctx     = qtilde;
    float* accpart = ws + 65536 + 524288;    // 2097152 floats

    hipLaunchKernelGGL(k_qs, dim3(256), dim3(256), 0, stream, q, wq, bq, qs);
    hipLaunchKernelGGL(k_qtilde, dim3(32, 8), dim3(256), 0, stream, qs, wk, qtilde);
    hipLaunchKernelGGL(k_fused3, dim3(64, 4), dim3(512), 0, stream,
                       kmat, qtilde, mask, attn, accpart, zpart);
    hipLaunchKernelGGL(k_combine, dim3(64, 4), dim3(256), 0, stream,
                       accpart, zpart, ctx, Zinv);
    hipLaunchKernelGGL(k_attnnorm, dim3(512), dim3(256), 0, stream, attn, Zinv);
    hipLaunchKernelGGL(k_out, dim3(256), dim3(256), 0, stream, ctx, wv, bv, out);
}